// Round 4
// baseline (113.408 us; speedup 1.0000x reference)
//
#include <hip/hip_runtime.h>
#include <math.h>

#define NB 8
#define NQ 100
#define NQH 50
#define NCP1 3
#define NC 2
#define HIN 128
#define WIN 128
#define HOUT 512
#define WOUT 512
#define QSTR (HIN * WIN)
#define QBYTES (QSTR * 4)

#if __has_builtin(__builtin_amdgcn_exp2f)
#define EXP2F(x) __builtin_amdgcn_exp2f(x)
#else
#define EXP2F(x) exp2f(x)
#endif
#if __has_builtin(__builtin_amdgcn_rcpf)
#define RCPF(x) __builtin_amdgcn_rcpf(x)
#else
#define RCPF(x) (1.0f / (x))
#endif
#if __has_builtin(__builtin_amdgcn_fractf)
#define FRACTF(x) __builtin_amdgcn_fractf(x)
#else
#define FRACTF(x) ((x) - floorf(x))
#endif

__device__ __forceinline__ float bperm(int byteaddr, float v) {
  return __int_as_float(__builtin_amdgcn_ds_bpermute(byteaddr, __float_as_int(v)));
}

// R16 = R15 + LDS sigmoid table (trans ops -> 0 in the main loop).
// R15 post-mortem: VALU issue = 142 cyc/wave-q (96 = 8 trans x 12cyc, 46
// regular); VALUBusy*dur = 22us matches; wall 45us = 1.9x issue floor.
// Trans is 68% of remaining issue AND a shared 1/4-rate unit that all 8
// symmetric waves burst on together.  R16: sigma = 2048-entry LDS table
// (float2 {sig_i, delta_i}, step 1/64 over t in [-16,16)) + linear interp.
// The x64+1024 index map folds FREE into the vertical-interp fmas
// (pre-scaled wlo/whi, bias inside the inner fma); midpoints commute with
// the affine map; bperm carries the scaled index u1 instead of t1.
// Per sigma: med3-clamp + cvt + fract + ds_read_b64 + fma = 4 VALU + 1 LDS
// gather (was exp2+add+rcp = 28 cyc).  Issue 142 -> ~74 cyc/wave-q.
// Table error ~3e-6 (quant) + <2e-5 (|t|>16 clamp) << R15's interp error:
// accuracy strictly improves.  LDS 9.2 -> 25.4KB, still 4 blocks/CU.
// Predict 45 -> 30-36us; bank-conflict counter goes nonzero (gathers).
__global__ __launch_bounds__(512, 4)
void m2f_fused(const float* __restrict__ cls,
               const float* __restrict__ masks,
               float* __restrict__ out) {
  const int k   = blockIdx.x;   // 0..127
  const int b   = blockIdx.y;   // 0..7
  const int tid = threadIdx.x;  // 0..511

  __shared__ float2 sigtab[2048];     // {sigma(t_i), sigma(t_{i+1})-sigma(t_i)}
  __shared__ float2 pq[NQ];           // (p_class0, p_class1) per q
  __shared__ float  part[8][256];     // qh=1 partials: [acc][r*64+lane]

  // ---- sigma table: sig(t) = 1/(1+2^t), t_i = i/64 - 16 ----
#pragma unroll
  for (int j = 0; j < 4; ++j) {
    const int i = tid + j * 512;
    const float x = (float)i * 0.015625f - 16.0f;
    const float s0 = RCPF(1.0f + EXP2F(x));
    const float s1 = RCPF(1.0f + EXP2F(x + 0.015625f));
    sigtab[i] = make_float2(s0, s1 - s0);
  }

  // ---- inline class softmax (keep first NC of NCP1) ----
  if (tid < NQ) {
    const float* cl = cls + (b * NQ + tid) * NCP1;
    float a0 = cl[0], a1 = cl[1], a2 = cl[2];
    float mx = fmaxf(a0, fmaxf(a1, a2));
    const float L2E = 1.4426950408889634f;
    float e0 = EXP2F((a0 - mx) * L2E);
    float e1 = EXP2F((a1 - mx) * L2E);
    float e2 = EXP2F((a2 - mx) * L2E);
    float inv = RCPF(e0 + e1 + e2);
    pq[tid] = make_float2(e0 * inv, e1 * inv);
  }
  __syncthreads();

  const int wave = tid >> 6;    // 0..7
  const int r    = wave & 3;    // output row phase (y = 4k+r)
  const int qh   = wave >> 2;   // q half: 0 -> q 0..49, 1 -> q 50..99
  const int lane = tid & 63;    // col group: x = 8*lane .. 8*lane+7
  const int q0   = qh * NQH;

  // clamped input rows + vertical weights.  t = -log2e * x (so sigma(x) =
  // 1/(1+2^t)); index u = 64*t + 1024 -> fold x64 into the weights and
  // +1024 into the inner fma.  Everything downstream works in u-space.
  const int rlo = (r < 2) ? (k > 0 ? k - 1 : 0) : k;
  const int rhi = (r < 2) ? k : (k < HIN - 1 ? k + 1 : HIN - 1);
  const float NL2E64 = -1.4426950408889634f * 64.0f;
  const float wlo = ((r == 0) ? 0.375f : (r == 1) ? 0.125f
                   : (r == 2) ? 0.875f : 0.625f) * NL2E64;
  const float whi = ((r == 0) ? 0.625f : (r == 1) ? 0.875f
                   : (r == 2) ? 0.125f : 0.375f) * NL2E64;

  // 32-bit byte voffsets with the q-half folded in (max ~6.6MB, fits 32b);
  // saddr stays block-uniform.
  const int voffA = q0 * QBYTES + (rlo * WIN + 2 * lane) * 4;
  const int voffB = q0 * QBYTES + (rhi * WIN + 2 * lane) * 4;
  const float* const basep = masks + (size_t)b * NQ * QSTR;  // block-uniform

  const int addrL = (lane - 1) << 2;
  const int addrR = (lane + 1) << 2;
  const bool edgeL = (lane == 0);
  const bool edgeR = (lane == 63);

  // accumulators: Sum_q pd * sigma at the 4 eval points (x=class0,y=class1)
  float2 aSL = make_float2(0.f, 0.f);
  float2 aS0 = make_float2(0.f, 0.f);
  float2 aSM = make_float2(0.f, 0.f);
  float2 aS1 = make_float2(0.f, 0.f);

  // depth-5 pipeline: 2 x float2 per stage (50 = 5*10, divides evenly)
  float2 A0, B0, A1, B1, A2, B2, A3, B3, A4, B4;

  // saddr-form loads: uniform SGPR-pair base + 32-bit VGPR voffset.
#define LOADSET(S, qrel)                                                  \
  do {                                                                    \
    asm volatile("global_load_dwordx2 %0, %2, %3\n\t"                     \
                 "global_load_dwordx2 %1, %4, %3"                         \
                 : "=&v"(A##S), "=&v"(B##S)                               \
                 : "v"(voffA + (qrel) * QBYTES), "s"(basep),              \
                   "v"(voffB + (qrel) * QBYTES));                         \
  } while (0)

  // steady state: 10 loads outstanding; stage S's pair is oldest -> wait
  // until <=8 remain.  Tied to stage regs so uses can't be hoisted above.
#define WAITS(S)                                                          \
  asm volatile("s_waitcnt vmcnt(8)" : "+v"(A##S), "+v"(B##S))

  // table sigmoid: u already = 64*t + 1024 from the load-interp fmas.
#define SIG(u, sout)                                                      \
  do {                                                                    \
    float uc = fminf(fmaxf((u), 0.0f), 2047.0f);                          \
    int   ii = (int)uc;                                                   \
    float fr = FRACTF(uc);                                                \
    float2 e = sigtab[ii];                                                \
    sout = fmaf(fr, e.y, e.x);                                            \
  } while (0)

#define COMPUTE(S, qq)                                                    \
  do {                                                                    \
    const float2 pd = pq[qq];                                             \
    float u0 = fmaf(wlo, A##S.x, fmaf(whi, B##S.x, 1024.0f));             \
    float u1 = fmaf(wlo, A##S.y, fmaf(whi, B##S.y, 1024.0f));             \
    float uLr = bperm(addrL, u1);                                         \
    float uL = edgeL ? u0 : uLr;                                          \
    float um  = 0.5f * (u0 + u1);                                         \
    float umL = 0.5f * (uL + u0);                                         \
    float sL, s0, sm, s1;                                                 \
    SIG(umL, sL);                                                         \
    SIG(u0,  s0);                                                         \
    SIG(um,  sm);                                                         \
    SIG(u1,  s1);                                                         \
    aSL.x = fmaf(pd.x, sL, aSL.x);  aSL.y = fmaf(pd.y, sL, aSL.y);        \
    aS0.x = fmaf(pd.x, s0, aS0.x);  aS0.y = fmaf(pd.y, s0, aS0.y);        \
    aSM.x = fmaf(pd.x, sm, aSM.x);  aSM.y = fmaf(pd.y, sm, aSM.y);        \
    aS1.x = fmaf(pd.x, s1, aS1.x);  aS1.y = fmaf(pd.y, s1, aS1.y);        \
  } while (0)

  LOADSET(0, 0); LOADSET(1, 1); LOADSET(2, 2); LOADSET(3, 3); LOADSET(4, 4);

  // main loop: qrel = 0,5,...,40 (each iteration prefetches qrel+5..qrel+9)
  for (int q = 0; q < NQH - 5; q += 5) {
    WAITS(0); COMPUTE(0, q0 + q);     LOADSET(0, q + 5);
    WAITS(1); COMPUTE(1, q0 + q + 1); LOADSET(1, q + 6);
    WAITS(2); COMPUTE(2, q0 + q + 2); LOADSET(2, q + 7);
    WAITS(3); COMPUTE(3, q0 + q + 3); LOADSET(3, q + 8);
    WAITS(4); COMPUTE(4, q0 + q + 4); LOADSET(4, q + 9);
  }

  // tail: drain all loads, then the final 5 stages (qrel 45..49)
  asm volatile("s_waitcnt vmcnt(0)"
               : "+v"(A0), "+v"(B0), "+v"(A1), "+v"(B1), "+v"(A2), "+v"(B2),
                 "+v"(A3), "+v"(B3), "+v"(A4), "+v"(B4));
  COMPUTE(0, q0 + NQH - 5);
  COMPUTE(1, q0 + NQH - 4);
  COMPUTE(2, q0 + NQH - 3);
  COMPUTE(3, q0 + NQH - 2);
  COMPUTE(4, q0 + NQH - 1);

  // ---- combine q-halves through LDS (8 floats/col, conflict-free) ----
  const int col = r * 64 + lane;
  if (qh == 1) {
    part[0][col] = aSL.x;  part[1][col] = aSL.y;
    part[2][col] = aS0.x;  part[3][col] = aS0.y;
    part[4][col] = aSM.x;  part[5][col] = aSM.y;
    part[6][col] = aS1.x;  part[7][col] = aS1.y;
  }
  __syncthreads();
  if (qh == 0) {
    aSL.x += part[0][col];  aSL.y += part[1][col];
    aS0.x += part[2][col];  aS0.y += part[3][col];
    aSM.x += part[4][col];  aSM.y += part[5][col];
    aS1.x += part[6][col];  aS1.y += part[7][col];

    // SR = neighbor's SL (bperm of the combined sum); edge lane: SR = S1
    float SRx_r = bperm(addrR, aSL.x);
    float SRy_r = bperm(addrR, aSL.y);
    float SRx = edgeR ? aS1.x : SRx_r;
    float SRy = edgeR ? aS1.y : SRy_r;

    // final half-gap interpolation (weights 0.75/0.25), once per wave
    float o0x = fmaf(0.25f, aS0.x, 0.75f * aSL.x);
    float o1x = fmaf(0.75f, aS0.x, 0.25f * aSL.x);
    float o2x = fmaf(0.25f, aSM.x, 0.75f * aS0.x);
    float o3x = fmaf(0.75f, aSM.x, 0.25f * aS0.x);
    float o4x = fmaf(0.25f, aS1.x, 0.75f * aSM.x);
    float o5x = fmaf(0.75f, aS1.x, 0.25f * aSM.x);
    float o6x = fmaf(0.25f, SRx,   0.75f * aS1.x);
    float o7x = fmaf(0.75f, SRx,   0.25f * aS1.x);
    float o0y = fmaf(0.25f, aS0.y, 0.75f * aSL.y);
    float o1y = fmaf(0.75f, aS0.y, 0.25f * aSL.y);
    float o2y = fmaf(0.25f, aSM.y, 0.75f * aS0.y);
    float o3y = fmaf(0.75f, aSM.y, 0.25f * aS0.y);
    float o4y = fmaf(0.25f, aS1.y, 0.75f * aSM.y);
    float o5y = fmaf(0.75f, aS1.y, 0.25f * aSM.y);
    float o6y = fmaf(0.25f, SRy,   0.75f * aS1.y);
    float o7y = fmaf(0.75f, SRy,   0.25f * aS1.y);

    const int y  = 4 * k + r;
    const int x0 = 8 * lane;
    float* o0 = out + (((size_t)b * NC + 0) * HOUT + y) * WOUT + x0;
    float* o1 = out + (((size_t)b * NC + 1) * HOUT + y) * WOUT + x0;
    *(float4*)o0       = make_float4(o0x, o1x, o2x, o3x);
    *(float4*)(o0 + 4) = make_float4(o4x, o5x, o6x, o7x);
    *(float4*)o1       = make_float4(o0y, o1y, o2y, o3y);
    *(float4*)(o1 + 4) = make_float4(o4y, o5y, o6y, o7y);
  }
}

extern "C" void kernel_launch(void* const* d_in, const int* in_sizes, int n_in,
                              void* d_out, int out_size, void* d_ws, size_t ws_size,
                              hipStream_t stream) {
  const float* cls   = (const float*)d_in[0];   // [8,100,3] fp32
  const float* masks = (const float*)d_in[1];   // [8,100,128,128] fp32
  float* out = (float*)d_out;                   // [8,2,512,512] fp32
  dim3 grid(HIN, NB);   // 128 k-groups x 8 batches, 8 waves/block
  m2f_fused<<<grid, 512, 0, stream>>>(cls, masks, out);
}

// Round 5
// 111.436 us; speedup vs baseline: 1.0177x; 1.0177x over previous
//
#include <hip/hip_runtime.h>
#include <math.h>

#define NB 8
#define NQ 100
#define NQH 50
#define NCP1 3
#define NC 2
#define HIN 128
#define WIN 128
#define HOUT 512
#define WOUT 512
#define QSTR (HIN * WIN)
#define QBYTES (QSTR * 4)

#if __has_builtin(__builtin_amdgcn_exp2f)
#define EXP2F(x) __builtin_amdgcn_exp2f(x)
#else
#define EXP2F(x) exp2f(x)
#endif
#if __has_builtin(__builtin_amdgcn_rcpf)
#define RCPF(x) __builtin_amdgcn_rcpf(x)
#else
#define RCPF(x) (1.0f / (x))
#endif

__device__ __forceinline__ float bperm(int byteaddr, float v) {
  return __int_as_float(__builtin_amdgcn_ds_bpermute(byteaddr, __float_as_int(v)));
}

// R17 = R16 with the LDS gathers shrunk 2.5x.  R16 post-mortem: wall 46us ==
// per-CU LDS-pipe time (4 blk/CU x 400 wave-q x [4 x (8cyc b64 + 4.3
// measured conflict cyc) + bperm + pq] ~ 43us).  The LDS pipe is PER-CU
// (shared by 4 SIMDs) -- its cycles are 4x as precious as SIMD-private
// VALU/trans cycles.  R16's float2 entries also used only the 16 even bank
// pairs.  Fixes:
//  - table = plain f32, NEAREST lookup (no {s,delta}, no interp fma): step
//    1/128 (4096 entries, 16KB).  Max sigma err = ln2/4/256 ~ 6.8e-4,
//    random-signed across q -> pixel ~1e-3, negligible vs tolerance.
//    Rounding +0.5 folds into the index bias (2048.5) - free.
//  - b32 gathers: 256B/wave base (2cyc min vs 4), banks spread over all 32
//    -> conflict cycles should ~halve (predict 6.9M -> 2-3.5M).
// Per wave-q: LDS ~36cyc (was ~65), VALU ~76cyc (~13us), trans 0.
// Predict 45 -> 31-37us.
__global__ __launch_bounds__(512, 4)
void m2f_fused(const float* __restrict__ cls,
               const float* __restrict__ masks,
               float* __restrict__ out) {
  const int k   = blockIdx.x;   // 0..127
  const int b   = blockIdx.y;   // 0..7
  const int tid = threadIdx.x;  // 0..511

  __shared__ float  sigtab[4096];     // sigma(t_i), t_i = i/128 - 16
  __shared__ float2 pq[NQ];           // (p_class0, p_class1) per q
  __shared__ float  part[8][256];     // qh=1 partials: [acc][r*64+lane]

  // ---- sigma table: sig(t) = 1/(1+2^t), nearest-neighbor ----
#pragma unroll
  for (int j = 0; j < 8; ++j) {
    const int i = tid + j * 512;
    const float x = (float)i * 0.0078125f - 16.0f;
    sigtab[i] = RCPF(1.0f + EXP2F(x));
  }

  // ---- inline class softmax (keep first NC of NCP1) ----
  if (tid < NQ) {
    const float* cl = cls + (b * NQ + tid) * NCP1;
    float a0 = cl[0], a1 = cl[1], a2 = cl[2];
    float mx = fmaxf(a0, fmaxf(a1, a2));
    const float L2E = 1.4426950408889634f;
    float e0 = EXP2F((a0 - mx) * L2E);
    float e1 = EXP2F((a1 - mx) * L2E);
    float e2 = EXP2F((a2 - mx) * L2E);
    float inv = RCPF(e0 + e1 + e2);
    pq[tid] = make_float2(e0 * inv, e1 * inv);
  }
  __syncthreads();

  const int wave = tid >> 6;    // 0..7
  const int r    = wave & 3;    // output row phase (y = 4k+r)
  const int qh   = wave >> 2;   // q half: 0 -> q 0..49, 1 -> q 50..99
  const int lane = tid & 63;    // col group: x = 8*lane .. 8*lane+7
  const int q0   = qh * NQH;

  // clamped input rows + vertical weights.  t = -log2e * x (sigma(x) =
  // 1/(1+2^t)); index u = 128*t + 2048.5 (+0.5 = rounding bias) -> fold
  // x128 into the weights and the bias into the inner fma.
  const int rlo = (r < 2) ? (k > 0 ? k - 1 : 0) : k;
  const int rhi = (r < 2) ? k : (k < HIN - 1 ? k + 1 : HIN - 1);
  const float NL2E128 = -1.4426950408889634f * 128.0f;
  const float wlo = ((r == 0) ? 0.375f : (r == 1) ? 0.125f
                   : (r == 2) ? 0.875f : 0.625f) * NL2E128;
  const float whi = ((r == 0) ? 0.625f : (r == 1) ? 0.875f
                   : (r == 2) ? 0.125f : 0.375f) * NL2E128;

  // 32-bit byte voffsets with the q-half folded in (max ~6.6MB, fits 32b);
  // saddr stays block-uniform.
  const int voffA = q0 * QBYTES + (rlo * WIN + 2 * lane) * 4;
  const int voffB = q0 * QBYTES + (rhi * WIN + 2 * lane) * 4;
  const float* const basep = masks + (size_t)b * NQ * QSTR;  // block-uniform

  const int addrL = (lane - 1) << 2;
  const int addrR = (lane + 1) << 2;
  const bool edgeL = (lane == 0);
  const bool edgeR = (lane == 63);

  // accumulators: Sum_q pd * sigma at the 4 eval points (x=class0,y=class1)
  float2 aSL = make_float2(0.f, 0.f);
  float2 aS0 = make_float2(0.f, 0.f);
  float2 aSM = make_float2(0.f, 0.f);
  float2 aS1 = make_float2(0.f, 0.f);

  // depth-5 pipeline: 2 x float2 per stage (50 = 5*10, divides evenly)
  float2 A0, B0, A1, B1, A2, B2, A3, B3, A4, B4;

  // saddr-form loads: uniform SGPR-pair base + 32-bit VGPR voffset.
#define LOADSET(S, qrel)                                                  \
  do {                                                                    \
    asm volatile("global_load_dwordx2 %0, %2, %3\n\t"                     \
                 "global_load_dwordx2 %1, %4, %3"                         \
                 : "=&v"(A##S), "=&v"(B##S)                               \
                 : "v"(voffA + (qrel) * QBYTES), "s"(basep),              \
                   "v"(voffB + (qrel) * QBYTES));                         \
  } while (0)

  // steady state: 10 loads outstanding; stage S's pair is oldest -> wait
  // until <=8 remain.  Tied to stage regs so uses can't be hoisted above.
#define WAITS(S)                                                          \
  asm volatile("s_waitcnt vmcnt(8)" : "+v"(A##S), "+v"(B##S))

  // nearest-entry table sigmoid: u already = 128*t + 2048.5
#define SIG(u, sout)                                                      \
  do {                                                                    \
    float uc = fminf(fmaxf((u), 0.0f), 4095.0f);                          \
    sout = sigtab[(int)uc];                                               \
  } while (0)

#define COMPUTE(S, qq)                                                    \
  do {                                                                    \
    const float2 pd = pq[qq];                                             \
    float u0 = fmaf(wlo, A##S.x, fmaf(whi, B##S.x, 2048.5f));             \
    float u1 = fmaf(wlo, A##S.y, fmaf(whi, B##S.y, 2048.5f));             \
    float uLr = bperm(addrL, u1);                                         \
    float uL = edgeL ? u0 : uLr;                                          \
    float um  = 0.5f * (u0 + u1);                                         \
    float umL = 0.5f * (uL + u0);                                         \
    float sL, s0, sm, s1;                                                 \
    SIG(umL, sL);                                                         \
    SIG(u0,  s0);                                                         \
    SIG(um,  sm);                                                         \
    SIG(u1,  s1);                                                         \
    aSL.x = fmaf(pd.x, sL, aSL.x);  aSL.y = fmaf(pd.y, sL, aSL.y);        \
    aS0.x = fmaf(pd.x, s0, aS0.x);  aS0.y = fmaf(pd.y, s0, aS0.y);        \
    aSM.x = fmaf(pd.x, sm, aSM.x);  aSM.y = fmaf(pd.y, sm, aSM.y);        \
    aS1.x = fmaf(pd.x, s1, aS1.x);  aS1.y = fmaf(pd.y, s1, aS1.y);        \
  } while (0)

  LOADSET(0, 0); LOADSET(1, 1); LOADSET(2, 2); LOADSET(3, 3); LOADSET(4, 4);

  // main loop: qrel = 0,5,...,40 (each iteration prefetches qrel+5..qrel+9)
  for (int q = 0; q < NQH - 5; q += 5) {
    WAITS(0); COMPUTE(0, q0 + q);     LOADSET(0, q + 5);
    WAITS(1); COMPUTE(1, q0 + q + 1); LOADSET(1, q + 6);
    WAITS(2); COMPUTE(2, q0 + q + 2); LOADSET(2, q + 7);
    WAITS(3); COMPUTE(3, q0 + q + 3); LOADSET(3, q + 8);
    WAITS(4); COMPUTE(4, q0 + q + 4); LOADSET(4, q + 9);
  }

  // tail: drain all loads, then the final 5 stages (qrel 45..49)
  asm volatile("s_waitcnt vmcnt(0)"
               : "+v"(A0), "+v"(B0), "+v"(A1), "+v"(B1), "+v"(A2), "+v"(B2),
                 "+v"(A3), "+v"(B3), "+v"(A4), "+v"(B4));
  COMPUTE(0, q0 + NQH - 5);
  COMPUTE(1, q0 + NQH - 4);
  COMPUTE(2, q0 + NQH - 3);
  COMPUTE(3, q0 + NQH - 2);
  COMPUTE(4, q0 + NQH - 1);

  // ---- combine q-halves through LDS (8 floats/col, conflict-free) ----
  const int col = r * 64 + lane;
  if (qh == 1) {
    part[0][col] = aSL.x;  part[1][col] = aSL.y;
    part[2][col] = aS0.x;  part[3][col] = aS0.y;
    part[4][col] = aSM.x;  part[5][col] = aSM.y;
    part[6][col] = aS1.x;  part[7][col] = aS1.y;
  }
  __syncthreads();
  if (qh == 0) {
    aSL.x += part[0][col];  aSL.y += part[1][col];
    aS0.x += part[2][col];  aS0.y += part[3][col];
    aSM.x += part[4][col];  aSM.y += part[5][col];
    aS1.x += part[6][col];  aS1.y += part[7][col];

    // SR = neighbor's SL (bperm of the combined sum); edge lane: SR = S1
    float SRx_r = bperm(addrR, aSL.x);
    float SRy_r = bperm(addrR, aSL.y);
    float SRx = edgeR ? aS1.x : SRx_r;
    float SRy = edgeR ? aS1.y : SRy_r;

    // final half-gap interpolation (weights 0.75/0.25), once per wave
    float o0x = fmaf(0.25f, aS0.x, 0.75f * aSL.x);
    float o1x = fmaf(0.75f, aS0.x, 0.25f * aSL.x);
    float o2x = fmaf(0.25f, aSM.x, 0.75f * aS0.x);
    float o3x = fmaf(0.75f, aSM.x, 0.25f * aS0.x);
    float o4x = fmaf(0.25f, aS1.x, 0.75f * aSM.x);
    float o5x = fmaf(0.75f, aS1.x, 0.25f * aSM.x);
    float o6x = fmaf(0.25f, SRx,   0.75f * aS1.x);
    float o7x = fmaf(0.75f, SRx,   0.25f * aS1.x);
    float o0y = fmaf(0.25f, aS0.y, 0.75f * aSL.y);
    float o1y = fmaf(0.75f, aS0.y, 0.25f * aSL.y);
    float o2y = fmaf(0.25f, aSM.y, 0.75f * aS0.y);
    float o3y = fmaf(0.75f, aSM.y, 0.25f * aS0.y);
    float o4y = fmaf(0.25f, aS1.y, 0.75f * aSM.y);
    float o5y = fmaf(0.75f, aS1.y, 0.25f * aSM.y);
    float o6y = fmaf(0.25f, SRy,   0.75f * aS1.y);
    float o7y = fmaf(0.75f, SRy,   0.25f * aS1.y);

    const int y  = 4 * k + r;
    const int x0 = 8 * lane;
    float* o0 = out + (((size_t)b * NC + 0) * HOUT + y) * WOUT + x0;
    float* o1 = out + (((size_t)b * NC + 1) * HOUT + y) * WOUT + x0;
    *(float4*)o0       = make_float4(o0x, o1x, o2x, o3x);
    *(float4*)(o0 + 4) = make_float4(o4x, o5x, o6x, o7x);
    *(float4*)o1       = make_float4(o0y, o1y, o2y, o3y);
    *(float4*)(o1 + 4) = make_float4(o4y, o5y, o6y, o7y);
  }
}

extern "C" void kernel_launch(void* const* d_in, const int* in_sizes, int n_in,
                              void* d_out, int out_size, void* d_ws, size_t ws_size,
                              hipStream_t stream) {
  const float* cls   = (const float*)d_in[0];   // [8,100,3] fp32
  const float* masks = (const float*)d_in[1];   // [8,100,128,128] fp32
  float* out = (float*)d_out;                   // [8,2,512,512] fp32
  dim3 grid(HIN, NB);   // 128 k-groups x 8 batches, 8 waves/block
  m2f_fused<<<grid, 512, 0, stream>>>(cls, masks, out);
}

// Round 6
// 111.333 us; speedup vs baseline: 1.0186x; 1.0009x over previous
//
#include <hip/hip_runtime.h>
#include <math.h>

#define NB 8
#define NQ 100
#define NQH 50
#define NCP1 3
#define NC 2
#define HIN 128
#define WIN 128
#define HOUT 512
#define WOUT 512
#define QSTR (HIN * WIN)
#define QBYTES (QSTR * 4)

#if __has_builtin(__builtin_amdgcn_exp2f)
#define EXP2F(x) __builtin_amdgcn_exp2f(x)
#else
#define EXP2F(x) exp2f(x)
#endif
#if __has_builtin(__builtin_amdgcn_rcpf)
#define RCPF(x) __builtin_amdgcn_rcpf(x)
#else
#define RCPF(x) (1.0f / (x))
#endif

__device__ __forceinline__ float bperm(int byteaddr, float v) {
  return __int_as_float(__builtin_amdgcn_ds_bpermute(byteaddr, __float_as_int(v)));
}

typedef float f32x4 __attribute__((ext_vector_type(4)));
typedef unsigned int u32x4 __attribute__((ext_vector_type(4)));

// R18 = R17 with the in-loop bperm DELETED (halo from global, right-side).
// R17 post-mortem: wall 44us with VALU pipe 18us (41%) and LDS pipe ~20us
// (46%) -- NEITHER saturated.  Diagnosis: latency-bound.  Per COMPUTE the
// chain was vmem -> u-fmas -> bperm (LDS round trip ~120cy) -> mids ->
// gather (2nd LDS round trip) -> accum: two chained LDS round-trips x 50
// iters at ~4-5 effective waves/SIMD doesn't hide.
// Fix: each lane buffer_load_dwordx4's cols 2l..2l+3 (8B-aligned) from both
// rows -> u0,u1 AND u2 (= right neighbor's u0) with no cross-lane op.  Gap
// bookkeeping mirrored right: accumulate aSR = sigma(mid(u1,u2)); epilogue
// bperm (1 per wave) brings SL from lane l-1; lane0/63 edges cndmask'd in
// the epilogue only.  Loads use a hand-rolled buffer SRD with num_records =
// per-batch window so lane63's 8B tail overrun (col 128/129) returns 0 --
// harmless: it only feeds lane63's aSR which edgeR already discards.
// Loop LDS chain depth 2 -> 1, LDS ops 6 -> 5/wave-q, loop edge logic gone.
// VGPR ~32 -> ~52 (still 8 waves/SIMD).  Predict 44 -> 34-39us, conflicts
// ~7.5M unchanged, VALUBusy% up to ~50-55.
__global__ __launch_bounds__(512, 4)
void m2f_fused(const float* __restrict__ cls,
               const float* __restrict__ masks,
               float* __restrict__ out) {
  const int k   = blockIdx.x;   // 0..127
  const int b   = blockIdx.y;   // 0..7
  const int tid = threadIdx.x;  // 0..511

  __shared__ float  sigtab[4096];     // sigma(t_i), t_i = i/128 - 16
  __shared__ float2 pq[NQ];           // (p_class0, p_class1) per q
  __shared__ float  part[8][256];     // qh=1 partials: [acc][r*64+lane]

  // ---- sigma table: sig(t) = 1/(1+2^t), nearest-neighbor ----
#pragma unroll
  for (int j = 0; j < 8; ++j) {
    const int i = tid + j * 512;
    const float x = (float)i * 0.0078125f - 16.0f;
    sigtab[i] = RCPF(1.0f + EXP2F(x));
  }

  // ---- inline class softmax (keep first NC of NCP1) ----
  if (tid < NQ) {
    const float* cl = cls + (b * NQ + tid) * NCP1;
    float a0 = cl[0], a1 = cl[1], a2 = cl[2];
    float mx = fmaxf(a0, fmaxf(a1, a2));
    const float L2E = 1.4426950408889634f;
    float e0 = EXP2F((a0 - mx) * L2E);
    float e1 = EXP2F((a1 - mx) * L2E);
    float e2 = EXP2F((a2 - mx) * L2E);
    float inv = RCPF(e0 + e1 + e2);
    pq[tid] = make_float2(e0 * inv, e1 * inv);
  }
  __syncthreads();

  const int wave = tid >> 6;    // 0..7
  const int r    = wave & 3;    // output row phase (y = 4k+r)
  const int qh   = wave >> 2;   // q half: 0 -> q 0..49, 1 -> q 50..99
  const int lane = tid & 63;    // col group: x = 8*lane .. 8*lane+7
  const int q0   = qh * NQH;

  // clamped input rows + vertical weights.  t = -log2e * x (sigma(x) =
  // 1/(1+2^t)); index u = 128*t + 2048.5 (+0.5 = rounding bias) -> fold
  // x128 into the weights and the bias into the inner fma.
  const int rlo = (r < 2) ? (k > 0 ? k - 1 : 0) : k;
  const int rhi = (r < 2) ? k : (k < HIN - 1 ? k + 1 : HIN - 1);
  const float NL2E128 = -1.4426950408889634f * 128.0f;
  const float wlo = ((r == 0) ? 0.375f : (r == 1) ? 0.125f
                   : (r == 2) ? 0.875f : 0.625f) * NL2E128;
  const float whi = ((r == 0) ? 0.625f : (r == 1) ? 0.875f
                   : (r == 2) ? 0.125f : 0.375f) * NL2E128;

  // buffer SRD over THIS batch's masks window: OOB (lane63 tail) reads 0.
  union { const float* p; unsigned long long u; } pn;
  pn.p = masks + (size_t)b * NQ * QSTR;
  u32x4 srd;
  srd.x = (unsigned int)pn.u;
  srd.y = (unsigned int)(pn.u >> 32) & 0xFFFFu;  // stride=0
  srd.z = (unsigned int)(NQ * QSTR * 4);         // num_records (bytes)
  srd.w = 0x00020000u;                           // raw dword access

  // 32-bit byte voffsets with the q-half folded in (max ~6.6MB, fits 32b)
  const int voffA = q0 * QBYTES + (rlo * WIN + 2 * lane) * 4;
  const int voffB = q0 * QBYTES + (rhi * WIN + 2 * lane) * 4;

  const int addrL = (lane - 1) << 2;
  const bool edgeL = (lane == 0);
  const bool edgeR = (lane == 63);

  // accumulators: Sum_q pd * sigma at the 4 eval points (x=class0,y=class1)
  float2 aS0 = make_float2(0.f, 0.f);
  float2 aSM = make_float2(0.f, 0.f);
  float2 aS1 = make_float2(0.f, 0.f);
  float2 aSR = make_float2(0.f, 0.f);   // sigma(mid(u1,u2)) = right-gap mid

  // depth-5 pipeline: 2 x f32x4 per stage (50 = 5*10, divides evenly)
  f32x4 A0, B0, A1, B1, A2, B2, A3, B3, A4, B4;

#define LOADSET(S, qrel)                                                  \
  do {                                                                    \
    asm volatile("buffer_load_dwordx4 %0, %2, %3, 0 offen\n\t"            \
                 "buffer_load_dwordx4 %1, %4, %3, 0 offen"                \
                 : "=&v"(A##S), "=&v"(B##S)                               \
                 : "v"(voffA + (qrel) * QBYTES), "s"(srd),                \
                   "v"(voffB + (qrel) * QBYTES));                         \
  } while (0)

  // steady state: 10 loads outstanding; stage S's pair is oldest -> wait
  // until <=8 remain.  Tied to stage regs so uses can't be hoisted above.
#define WAITS(S)                                                          \
  asm volatile("s_waitcnt vmcnt(8)" : "+v"(A##S), "+v"(B##S))

  // nearest-entry table sigmoid: u already = 128*t + 2048.5
#define SIG(u, sout)                                                      \
  do {                                                                    \
    float uc = fminf(fmaxf((u), 0.0f), 4095.0f);                          \
    sout = sigtab[(int)uc];                                               \
  } while (0)

#define COMPUTE(S, qq)                                                    \
  do {                                                                    \
    const float2 pd = pq[qq];                                             \
    float u0 = fmaf(wlo, A##S.x, fmaf(whi, B##S.x, 2048.5f));             \
    float u1 = fmaf(wlo, A##S.y, fmaf(whi, B##S.y, 2048.5f));             \
    float u2 = fmaf(wlo, A##S.z, fmaf(whi, B##S.z, 2048.5f));             \
    float um  = 0.5f * (u0 + u1);                                         \
    float umR = 0.5f * (u1 + u2);                                         \
    float s0, sm, s1, sR;                                                 \
    SIG(u0,  s0);                                                         \
    SIG(um,  sm);                                                         \
    SIG(u1,  s1);                                                         \
    SIG(umR, sR);                                                         \
    aS0.x = fmaf(pd.x, s0, aS0.x);  aS0.y = fmaf(pd.y, s0, aS0.y);        \
    aSM.x = fmaf(pd.x, sm, aSM.x);  aSM.y = fmaf(pd.y, sm, aSM.y);        \
    aS1.x = fmaf(pd.x, s1, aS1.x);  aS1.y = fmaf(pd.y, s1, aS1.y);        \
    aSR.x = fmaf(pd.x, sR, aSR.x);  aSR.y = fmaf(pd.y, sR, aSR.y);        \
  } while (0)

  LOADSET(0, 0); LOADSET(1, 1); LOADSET(2, 2); LOADSET(3, 3); LOADSET(4, 4);

  // main loop: qrel = 0,5,...,40 (each iteration prefetches qrel+5..qrel+9)
  for (int q = 0; q < NQH - 5; q += 5) {
    WAITS(0); COMPUTE(0, q0 + q);     LOADSET(0, q + 5);
    WAITS(1); COMPUTE(1, q0 + q + 1); LOADSET(1, q + 6);
    WAITS(2); COMPUTE(2, q0 + q + 2); LOADSET(2, q + 7);
    WAITS(3); COMPUTE(3, q0 + q + 3); LOADSET(3, q + 8);
    WAITS(4); COMPUTE(4, q0 + q + 4); LOADSET(4, q + 9);
  }

  // tail: drain all loads, then the final 5 stages (qrel 45..49)
  asm volatile("s_waitcnt vmcnt(0)"
               : "+v"(A0), "+v"(B0), "+v"(A1), "+v"(B1), "+v"(A2), "+v"(B2),
                 "+v"(A3), "+v"(B3), "+v"(A4), "+v"(B4));
  COMPUTE(0, q0 + NQH - 5);
  COMPUTE(1, q0 + NQH - 4);
  COMPUTE(2, q0 + NQH - 3);
  COMPUTE(3, q0 + NQH - 2);
  COMPUTE(4, q0 + NQH - 1);

  // ---- combine q-halves through LDS (8 floats/col, conflict-free) ----
  const int col = r * 64 + lane;
  if (qh == 1) {
    part[0][col] = aS0.x;  part[1][col] = aS0.y;
    part[2][col] = aSM.x;  part[3][col] = aSM.y;
    part[4][col] = aS1.x;  part[5][col] = aS1.y;
    part[6][col] = aSR.x;  part[7][col] = aSR.y;
  }
  __syncthreads();
  if (qh == 0) {
    aS0.x += part[0][col];  aS0.y += part[1][col];
    aSM.x += part[2][col];  aSM.y += part[3][col];
    aS1.x += part[4][col];  aS1.y += part[5][col];
    aSR.x += part[6][col];  aSR.y += part[7][col];

    // SL = left neighbor's aSR (bperm of combined sum); lane 0: SL = S0.
    // SR = own aSR; lane 63: SR = S1 (right-edge clamp, discards the
    // OOB-fed accumulator).
    float SLx_r = bperm(addrL, aSR.x);
    float SLy_r = bperm(addrL, aSR.y);
    float SLx = edgeL ? aS0.x : SLx_r;
    float SLy = edgeL ? aS0.y : SLy_r;
    float SRx = edgeR ? aS1.x : aSR.x;
    float SRy = edgeR ? aS1.y : aSR.y;

    // final half-gap interpolation (weights 0.75/0.25), once per wave
    float o0x = fmaf(0.25f, aS0.x, 0.75f * SLx);
    float o1x = fmaf(0.75f, aS0.x, 0.25f * SLx);
    float o2x = fmaf(0.25f, aSM.x, 0.75f * aS0.x);
    float o3x = fmaf(0.75f, aSM.x, 0.25f * aS0.x);
    float o4x = fmaf(0.25f, aS1.x, 0.75f * aSM.x);
    float o5x = fmaf(0.75f, aS1.x, 0.25f * aSM.x);
    float o6x = fmaf(0.25f, SRx,   0.75f * aS1.x);
    float o7x = fmaf(0.75f, SRx,   0.25f * aS1.x);
    float o0y = fmaf(0.25f, aS0.y, 0.75f * SLy);
    float o1y = fmaf(0.75f, aS0.y, 0.25f * SLy);
    float o2y = fmaf(0.25f, aSM.y, 0.75f * aS0.y);
    float o3y = fmaf(0.75f, aSM.y, 0.25f * aS0.y);
    float o4y = fmaf(0.25f, aS1.y, 0.75f * aSM.y);
    float o5y = fmaf(0.75f, aS1.y, 0.25f * aSM.y);
    float o6y = fmaf(0.25f, SRy,   0.75f * aS1.y);
    float o7y = fmaf(0.75f, SRy,   0.25f * aS1.y);

    const int y  = 4 * k + r;
    const int x0 = 8 * lane;
    float* o0 = out + (((size_t)b * NC + 0) * HOUT + y) * WOUT + x0;
    float* o1 = out + (((size_t)b * NC + 1) * HOUT + y) * WOUT + x0;
    *(float4*)o0       = make_float4(o0x, o1x, o2x, o3x);
    *(float4*)(o0 + 4) = make_float4(o4x, o5x, o6x, o7x);
    *(float4*)o1       = make_float4(o0y, o1y, o2y, o3y);
    *(float4*)(o1 + 4) = make_float4(o4y, o5y, o6y, o7y);
  }
}

extern "C" void kernel_launch(void* const* d_in, const int* in_sizes, int n_in,
                              void* d_out, int out_size, void* d_ws, size_t ws_size,
                              hipStream_t stream) {
  const float* cls   = (const float*)d_in[0];   // [8,100,3] fp32
  const float* masks = (const float*)d_in[1];   // [8,100,128,128] fp32
  float* out = (float*)d_out;                   // [8,2,512,512] fp32
  dim3 grid(HIN, NB);   // 128 k-groups x 8 batches, 8 waves/block
  m2f_fused<<<grid, 512, 0, stream>>>(cls, masks, out);
}